// Round 18
// baseline (901.974 us; speedup 1.0000x reference)
//
#include <hip/hip_runtime.h>
#include <cstdint>

typedef unsigned long long u64;
typedef unsigned int u32;
typedef unsigned short ushort;
typedef __attribute__((ext_vector_type(8))) short short8;
typedef __attribute__((ext_vector_type(4))) float f32x4;

#define A_TOTAL 261888   // 3 * 87296 anchors
#define NPIX    87296
#define KTOP    6000
#define KTARGET 7800     // screen candidate target (slack for bf16 screen error)
#define NWORDS  94       // ceil(6000/64)
#define CANDMAX 8192
#define PIXMAX  8192
#define NBINS   16384    // 14-bit fp32-key bins

__device__ __forceinline__ u64 score_key64(double s) {
  u64 u = (u64)__double_as_longlong(s);
  return (u & 0x8000000000000000ULL) ? ~u : (u | 0x8000000000000000ULL);
}
__device__ __forceinline__ u32 key32(float s) {
  u32 u = __float_as_uint(s);
  return (u & 0x80000000u) ? ~u : (u | 0x80000000u);
}
__device__ __forceinline__ ushort f2bf(float f) {   // RNE fp32->bf16 (finite inputs)
  u32 u = __float_as_uint(f);
  u32 r = (u + 0x7FFFu + ((u >> 16) & 1u)) >> 16;
  return (ushort)r;
}
__device__ __forceinline__ void pix_level(int pix, int& l, int& off) {
  if (pix < 65536)      { l = 0; off = 0; }
  else if (pix < 81920) { l = 1; off = 65536; }
  else if (pix < 86016) { l = 2; off = 81920; }
  else if (pix < 87040) { l = 3; off = 86016; }
  else                  { l = 4; off = 87040; }
}

// ---------------- weight prep: wt64 fp64 [k][oc] (exact fp32 values) + wkf bf16 ---
__global__ void k_prep_w(const float* __restrict__ w0, double* __restrict__ wt64,
                         ushort* __restrict__ wkf) {
  int i = blockIdx.x * 256 + threadIdx.x;
  if (i < 256 * 2304) {
    int o = i & 255;
    int ictap = i >> 8;
    float v = w0[o * 2304 + ictap];
    wt64[(size_t)ictap * 256 + o] = (double)v;
    int ic = ictap / 9;
    int tap = ictap - ic * 9;
    int w = o >> 6, mt = (o >> 4) & 3, l15 = o & 15;
    int ch = ic >> 5, kk = ic & 31;
    int l4 = kk >> 3, e = kk & 7;
    int lane = l4 * 16 + l15;
    wkf[((((w * 4 + mt) * 8 + ch) * 9 + tap) << 9) + lane * 8 + e] = f2bf(v);
  }
}

// ---------------- MFMA bf16 screening conv (round-14 structure) -------------------
__global__ __launch_bounds__(256, 2) void k_conv_mfma(
    const float* __restrict__ f0, const float* __restrict__ f1,
    const float* __restrict__ f2, const float* __restrict__ f3,
    const float* __restrict__ f4,
    const ushort* __restrict__ wkf, const float* __restrict__ b0,
    const float* __restrict__ wcls, const float* __restrict__ bcls,
    float* __restrict__ scr)
{
  __shared__ ushort xsl[100][40];        // [halo sp][32 ic +8 pad]  8.0 KB
  __shared__ float  part[3][64][17];     // head partials           13.1 KB

  int b = blockIdx.x;
  int l, tb;
  if (b < 1024)      { l = 0; tb = b; }
  else if (b < 1280) { l = 1; tb = b - 1024; }
  else if (b < 1344) { l = 2; tb = b - 1280; }
  else if (b < 1360) { l = 3; tb = b - 1344; }
  else               { l = 4; tb = b - 1360; }
  const float* feat = (l == 0) ? f0 : (l == 1) ? f1 : (l == 2) ? f2 : (l == 3) ? f3 : f4;
  int Hh = 256 >> l;
  int HW = Hh * Hh;
  int pixOff = (l == 0) ? 0 : (l == 1) ? 65536 : (l == 2) ? 81920 : (l == 3) ? 86016 : 87040;
  int shl = 5 - l;
  int ty = (tb >> shl) << 3;
  int tx = (tb & ((1 << shl) - 1)) << 3;

  int tid = threadIdx.x;
  int w = tid >> 6;
  int lane = tid & 63;
  int l15 = lane & 15;
  int l4 = lane >> 4;

  f32x4 zz = {0.f, 0.f, 0.f, 0.f};
  f32x4 acc[4][4];
  #pragma unroll
  for (int mt = 0; mt < 4; ++mt)
    #pragma unroll
    for (int tt = 0; tt < 4; ++tt) acc[mt][tt] = zz;

  for (int ch = 0; ch < 8; ++ch) {
    __syncthreads();
    for (int e = tid; e < 3200; e += 256) {
      int icl = e / 100;
      int sp = e - icl * 100;
      int yy = sp / 10;
      int xx = sp - yy * 10;
      int gy = ty + yy - 1, gx = tx + xx - 1;
      float v = 0.f;
      if (gy >= 0 && gy < Hh && gx >= 0 && gx < Hh)
        v = feat[(ch * 32 + icl) * HW + gy * Hh + gx];
      xsl[sp][icl] = f2bf(v);
    }
    __syncthreads();
    #pragma unroll
    for (int tap = 0; tap < 9; ++tap) {
      int dy = tap / 3;
      int dx = tap - dy * 3;
      short8 af[4], bf[4];
      #pragma unroll
      for (int mt = 0; mt < 4; ++mt) {
        int abase = ((((w * 4 + mt) * 8 + ch) * 9 + tap) << 9) + (lane << 3);
        af[mt] = *(const short8*)(wkf + abase);
      }
      #pragma unroll
      for (int tt = 0; tt < 4; ++tt) {
        int p = (tt << 4) + l15;
        int sp = ((p >> 3) + dy) * 10 + (p & 7) + dx;
        bf[tt] = *(const short8*)&xsl[sp][l4 << 3];
      }
      #pragma unroll
      for (int mt = 0; mt < 4; ++mt)
        #pragma unroll
        for (int tt = 0; tt < 4; ++tt)
          acc[mt][tt] = __builtin_amdgcn_mfma_f32_16x16x32_bf16(af[mt], bf[tt], acc[mt][tt], 0, 0, 0);
    }
  }

  float pr[3][4];
  #pragma unroll
  for (int kk = 0; kk < 3; ++kk)
    #pragma unroll
    for (int tt = 0; tt < 4; ++tt) pr[kk][tt] = 0.f;
  #pragma unroll
  for (int mt = 0; mt < 4; ++mt) {
    #pragma unroll
    for (int r = 0; r < 4; ++r) {
      int oc = (w << 6) + (mt << 4) + (l4 << 2) + r;
      float bb = b0[oc];
      float c0 = wcls[oc], c1 = wcls[256 + oc], c2 = wcls[512 + oc];
      #pragma unroll
      for (int tt = 0; tt < 4; ++tt) {
        float v = acc[mt][tt][r] + bb;
        v = v > 0.f ? v : 0.f;
        pr[0][tt] = fmaf(c0, v, pr[0][tt]);
        pr[1][tt] = fmaf(c1, v, pr[1][tt]);
        pr[2][tt] = fmaf(c2, v, pr[2][tt]);
      }
    }
  }
  __syncthreads();
  #pragma unroll
  for (int kk = 0; kk < 3; ++kk)
    #pragma unroll
    for (int tt = 0; tt < 4; ++tt)
      part[kk][(tt << 4) + l15][(w << 2) + l4] = pr[kk][tt];
  __syncthreads();
  if (tid < 192) {
    int kk = tid >> 6;
    int px = tid & 63;
    float s = 0.f;
    #pragma unroll
    for (int q = 0; q < 16; ++q) s += part[kk][px][q];
    int pix = pixOff + (ty + (px >> 3)) * Hh + (tx + (px & 7));
    scr[pix * 3 + kk] = s + bcls[kk];
  }
}

// ---------------- exact two-level threshold selection (count-targeted) ------------
__global__ void k_hist1(const float* __restrict__ scr, u32* __restrict__ bins) {
  __shared__ u32 h[NBINS];
  int tid = threadIdx.x;
  for (int idx = tid; idx < NBINS; idx += 256) h[idx] = 0;
  __syncthreads();
  for (int i = blockIdx.x * 256 + tid; i < A_TOTAL; i += gridDim.x * 256)
    atomicAdd(&h[key32(scr[i]) >> 18], 1u);
  __syncthreads();
  for (int idx = tid; idx < NBINS; idx += 256) {
    u32 v = h[idx];
    if (v) atomicAdd(&bins[idx], v);
  }
}

__global__ void k_scan1(const u32* __restrict__ bins, u32* __restrict__ meta) {
  __shared__ u32 psum[256];
  int tid = threadIdx.x;
  u32 s = 0;
  for (int u = 0; u < 64; ++u) s += bins[tid * 64 + u];
  psum[tid] = s;
  __syncthreads();
  if (tid == 0) {
    u32 run = 0;
    for (int t = 255; t >= 0; --t) { u32 tmp = psum[t]; psum[t] = run; run += tmp; }
  }
  __syncthreads();
  u32 cum = psum[tid];
  if (cum < (u32)KTARGET) {
    for (int u = 63; u >= 0; --u) {
      u32 bv = bins[tid * 64 + u];
      u32 nc = cum + bv;
      if (nc >= (u32)KTARGET) {
        meta[0] = (u32)(tid * 64 + u);
        meta[2] = cum;
        break;
      }
      cum = nc;
    }
  }
}

__global__ void k_hist2(const float* __restrict__ scr, const u32* __restrict__ meta,
                        u32* __restrict__ sub) {
  int i = blockIdx.x * 256 + threadIdx.x;
  if (i < A_TOTAL) {
    u32 k = key32(scr[i]);
    if ((k >> 18) == meta[0]) atomicAdd(&sub[(k >> 10) & 0xFFu], 1u);
  }
}

__global__ void k_scan2(const u32* __restrict__ sub, u32* __restrict__ meta) {
  if (threadIdx.x == 0) {
    u32 b = meta[0];
    u32 c = meta[2];
    u32 T = b << 18;
    for (int u = 255; u >= 0; --u) {
      c += sub[u];
      if (c >= (u32)KTARGET) { T = (b << 18) | ((u32)u << 10); break; }
    }
    meta[3] = (T >= (2u << 10)) ? (T - (2u << 10)) : 0u;
  }
}

// ---------------- fused ordered compaction: anchors + pixels ----------------------
__global__ void k_cnt2(const float* __restrict__ scr, const u32* __restrict__ meta,
                       u32* __restrict__ blkCnt, u32* __restrict__ blkCntP) {
  __shared__ u32 wc[4], wcp[4];
  int tid = threadIdx.x;
  int lane = tid & 63, wv = tid >> 6;
  u32 T = meta[3];
  int i = blockIdx.x * 256 + tid;
  bool qa = (i < A_TOTAL) && (key32(scr[i]) >= T);
  u64 ba = __ballot(qa);
  bool qp = false;
  if (i < NPIX)
    qp = (key32(scr[i * 3 + 0]) >= T) || (key32(scr[i * 3 + 1]) >= T) || (key32(scr[i * 3 + 2]) >= T);
  u64 bp = __ballot(qp);
  if (lane == 0) { wc[wv] = (u32)__popcll(ba); wcp[wv] = (u32)__popcll(bp); }
  __syncthreads();
  if (tid == 0) {
    blkCnt[blockIdx.x]  = wc[0] + wc[1] + wc[2] + wc[3];
    blkCntP[blockIdx.x] = wcp[0] + wcp[1] + wcp[2] + wcp[3];
  }
}

__global__ __launch_bounds__(1024) void k_scanblk2(const u32* __restrict__ blkCnt,
                                                   u32* __restrict__ blkOff,
                                                   u32* __restrict__ totA,
                                                   const u32* __restrict__ blkCntP,
                                                   u32* __restrict__ blkOffP,
                                                   u32* __restrict__ totP) {
  __shared__ u32 buf[2][1024];
  int tid = threadIdx.x;
  for (int pass = 0; pass < 2; ++pass) {
    const u32* src_ = pass ? blkCntP : blkCnt;
    u32* dst_ = pass ? blkOffP : blkOff;
    u32* tot_ = pass ? totP : totA;
    u32 v = (tid < 1023) ? src_[tid] : 0u;
    buf[0][tid] = v;
    __syncthreads();
    int src = 0;
    for (int d = 1; d < 1024; d <<= 1) {
      u32 t = buf[src][tid] + ((tid >= d) ? buf[src][tid - d] : 0u);
      buf[src ^ 1][tid] = t;
      src ^= 1;
      __syncthreads();
    }
    if (tid < 1023) dst_[tid] = buf[src][tid] - v;
    if (tid == 0) tot_[0] = buf[src][1022];
    __syncthreads();
  }
}

__global__ void k_fill2(const float* __restrict__ scr, const u32* __restrict__ meta,
                        const u32* __restrict__ blkOff, const u32* __restrict__ blkOffP,
                        u32* __restrict__ candIdx, u32* __restrict__ pixList,
                        u32* __restrict__ pixMap) {
  __shared__ u32 wbase[4], wbaseP[4];
  int tid = threadIdx.x;
  int lane = tid & 63, wv = tid >> 6;
  u32 T = meta[3];
  int i = blockIdx.x * 256 + tid;
  bool qa = (i < A_TOTAL) && (key32(scr[i]) >= T);
  u64 ba = __ballot(qa);
  bool qp = false;
  if (i < NPIX)
    qp = (key32(scr[i * 3 + 0]) >= T) || (key32(scr[i * 3 + 1]) >= T) || (key32(scr[i * 3 + 2]) >= T);
  u64 bp = __ballot(qp);
  if (lane == 0) { wbase[wv] = (u32)__popcll(ba); wbaseP[wv] = (u32)__popcll(bp); }
  __syncthreads();
  if (tid == 0) {
    u32 r = blkOff[blockIdx.x];
    #pragma unroll
    for (int w2 = 0; w2 < 4; ++w2) { u32 t = wbase[w2]; wbase[w2] = r; r += t; }
    u32 rp = blkOffP[blockIdx.x];
    #pragma unroll
    for (int w2 = 0; w2 < 4; ++w2) { u32 t = wbaseP[w2]; wbaseP[w2] = rp; rp += t; }
  }
  __syncthreads();
  if (qa) {
    u32 rank = (u32)__popcll(ba & ((1ULL << lane) - 1ULL));
    u32 pos = wbase[wv] + rank;
    if (pos < CANDMAX) candIdx[pos] = (u32)i;
  }
  if (qp) {
    u32 rank = (u32)__popcll(bp & ((1ULL << lane) - 1ULL));
    u32 pos = wbaseP[wv] + rank;
    if (pos < PIXMAX) { pixList[pos] = (u32)i; pixMap[i] = pos; }
  }
}

// ---------------- exact fp64 hidden: single-buffer fp64 patch, 8 blocks/CU --------
// Patch 18.4KB (no dbuf) -> 8 blocks/CU (8 waves/SIMD) for latency hiding.
// Per k-step: 16 fp64 FMA + 4 mem loads, zero cvt. kc-major keeps each 1.18MB
// fp64 weight quarter L2-resident.
#define KCH 144
__global__ __launch_bounds__(256, 8) void k_hidden(
    const float* __restrict__ f0, const float* __restrict__ f1,
    const float* __restrict__ f2, const float* __restrict__ f3,
    const float* __restrict__ f4,
    const double* __restrict__ wt64,
    const u32* __restrict__ pixList, const u32* __restrict__ meta,
    double* __restrict__ hpart)
{
  __shared__ double patch[KCH][16];       // 18.4 KB
  __shared__ int sValid[16], sY[16], sX[16], sW[16], sL[16];

  int tid = threadIdx.x;
  int pixblk = blockIdx.x & 511;          // PIXMAX/16 - 1
  int kc = blockIdx.x >> 9;
  int base = pixblk * 16;
  u32 np = meta[4];
  if (np > PIXMAX) np = PIXMAX;
  if (base >= (int)np) return;

  if (tid < 16) {
    int slot = base + tid;
    int v = slot < (int)np;
    sValid[tid] = v;
    int pix = v ? (int)pixList[slot] : 0;
    int l, off;
    pix_level(pix, l, off);
    int W = 256 >> l;
    int idx = pix - off;
    sL[tid] = l;
    sW[tid] = W;
    sY[tid] = idx >> (8 - l);
    sX[tid] = idx & (W - 1);
  }
  __syncthreads();

  // chunk cb covers ic range [cb*16, cb*16+16), k = ic*9 + tap
  auto stage = [&](int cb) {
    for (int t = tid; t < 768; t += 256) {
      int s = t & 15;
      int rem = t >> 4;                   // 0..47 = icl*3 + dy
      int icl = rem / 3;
      int dy = rem - icl * 3;
      int ic = cb * 16 + icl;
      float v0 = 0.f, v1 = 0.f, v2 = 0.f;
      if (sValid[s]) {
        int l = sL[s], W = sW[s], y = sY[s], x = sX[s];
        const float* feat = (l == 0) ? f0 : (l == 1) ? f1 : (l == 2) ? f2 : (l == 3) ? f3 : f4;
        int gy = y + dy - 1;
        if (gy >= 0 && gy < W) {
          const float* rowp = feat + ic * W * W + gy * W;
          if (x - 1 >= 0) v0 = rowp[x - 1];
          v1 = rowp[x];
          if (x + 1 < W) v2 = rowp[x + 1];
        }
      }
      int kb = icl * 9 + dy * 3;
      patch[kb + 0][s] = (double)v0;      // widen once at staging
      patch[kb + 1][s] = (double)v1;
      patch[kb + 2][s] = (double)v2;
    }
  };

  int ocq = tid & 63;                     // oc quad: oc = ocq*4 .. +3
  int pxq = tid >> 6;                     // px quad (wave-uniform)

  double acc[4][4];
  #pragma unroll
  for (int i = 0; i < 4; ++i)
    #pragma unroll
    for (int j = 0; j < 4; ++j) acc[i][j] = 0.0;

  int cb0 = kc * 4;                       // 16 chunks total, 4 per kc
  for (int i = 0; i < 4; ++i) {
    int cb = cb0 + i;
    if (i) __syncthreads();               // prior chunk's patch reads done
    stage(cb);
    __syncthreads();                      // staging visible
    const double* wb_ = wt64 + (size_t)(cb * KCH) * 256 + (ocq << 2);
    for (int kk = 0; kk < KCH; ++kk) {
      const double* pp = &patch[kk][pxq << 2];       // broadcast (2x ds_read_b128)
      double pd0 = pp[0], pd1 = pp[1], pd2 = pp[2], pd3 = pp[3];
      const double* wr = wb_ + (size_t)kk * 256;     // coalesced 2KB/wave
      double w0_ = wr[0], w1_ = wr[1], w2_ = wr[2], w3_ = wr[3];
      acc[0][0] = fma(w0_, pd0, acc[0][0]);
      acc[0][1] = fma(w0_, pd1, acc[0][1]);
      acc[0][2] = fma(w0_, pd2, acc[0][2]);
      acc[0][3] = fma(w0_, pd3, acc[0][3]);
      acc[1][0] = fma(w1_, pd0, acc[1][0]);
      acc[1][1] = fma(w1_, pd1, acc[1][1]);
      acc[1][2] = fma(w1_, pd2, acc[1][2]);
      acc[1][3] = fma(w1_, pd3, acc[1][3]);
      acc[2][0] = fma(w2_, pd0, acc[2][0]);
      acc[2][1] = fma(w2_, pd1, acc[2][1]);
      acc[2][2] = fma(w2_, pd2, acc[2][2]);
      acc[2][3] = fma(w2_, pd3, acc[2][3]);
      acc[3][0] = fma(w3_, pd0, acc[3][0]);
      acc[3][1] = fma(w3_, pd1, acc[3][1]);
      acc[3][2] = fma(w3_, pd2, acc[3][2]);
      acc[3][3] = fma(w3_, pd3, acc[3][3]);
    }
  }

  #pragma unroll
  for (int j = 0; j < 4; ++j) {
    int s = (pxq << 2) + j;
    if (sValid[s]) {
      double* dst = &hpart[((size_t)kc * PIXMAX + base + s) * 256 + (ocq << 2)];
      dst[0] = acc[0][j];
      dst[1] = acc[1][j];
      dst[2] = acc[2][j];
      dst[3] = acc[3][j];
    }
  }
}

// ---------------- exact fp64 heads per candidate anchor (combines K-partials) -----
__global__ __launch_bounds__(256, 4) void k_heads(
    const float* __restrict__ wcls, const float* __restrict__ bcls,
    const float* __restrict__ wbox, const float* __restrict__ bbox,
    const float* __restrict__ b0,
    const u32* __restrict__ candIdx, const u32* __restrict__ pixMap,
    const u32* __restrict__ meta, const double* __restrict__ hpart,
    u64* __restrict__ candKey, u32* __restrict__ candPack, double* __restrict__ candDelta)
{
  __shared__ double wavePart[8][5][4];
  __shared__ int sIdx[8], sValid[8], sR[8], sPS[8];
  int tid = threadIdx.x;
  int lane = tid & 63;
  int wv = tid >> 6;
  int base = blockIdx.x * 8;
  u32 cnt = meta[1];
  if (cnt > CANDMAX) cnt = CANDMAX;

  if (base >= (int)cnt) {
    if (tid < 8) {
      candKey[base + tid] = 0ULL;
      candPack[base + tid] = 0xFFFFFFFFu;
    }
    return;
  }

  if (tid < 8) {
    int slot = base + tid;
    int v = slot < (int)cnt;
    sValid[tid] = v;
    int aidx = v ? (int)candIdx[slot] : 0;
    sIdx[tid] = aidx;
    int pix = aidx / 3;
    sR[tid] = aidx - pix * 3;
    sPS[tid] = v ? (int)pixMap[pix] : 0;
  }
  __syncthreads();

  double bb = (double)b0[tid];
  for (int s = 0; s < 8; ++s) {
    if (!sValid[s]) continue;
    int r = sR[s];
    size_t ps = (size_t)sPS[s];
    double hv = hpart[ps * 256 + tid];
    hv = hv + hpart[((size_t)PIXMAX + ps) * 256 + tid];
    hv = hv + hpart[((size_t)2 * PIXMAX + ps) * 256 + tid];
    hv = hv + hpart[((size_t)3 * PIXMAX + ps) * 256 + tid];
    hv = hv + bb;
    hv = hv > 0.0 ? hv : 0.0;
    double p0 = (double)wcls[r * 256 + tid] * hv;
    double p1 = (double)wbox[(r * 4 + 0) * 256 + tid] * hv;
    double p2 = (double)wbox[(r * 4 + 1) * 256 + tid] * hv;
    double p3 = (double)wbox[(r * 4 + 2) * 256 + tid] * hv;
    double p4 = (double)wbox[(r * 4 + 3) * 256 + tid] * hv;
    #pragma unroll
    for (int d = 32; d; d >>= 1) {
      p0 += __shfl_xor(p0, d);
      p1 += __shfl_xor(p1, d);
      p2 += __shfl_xor(p2, d);
      p3 += __shfl_xor(p3, d);
      p4 += __shfl_xor(p4, d);
    }
    if (lane == 0) {
      wavePart[s][0][wv] = p0;
      wavePart[s][1][wv] = p1;
      wavePart[s][2][wv] = p2;
      wavePart[s][3][wv] = p3;
      wavePart[s][4][wv] = p4;
    }
  }
  __syncthreads();
  if (tid < 40) {
    int s = tid / 5;
    int k = tid - s * 5;
    int slot = base + s;
    if (sValid[s]) {
      double v = wavePart[s][k][0] + wavePart[s][k][1] + wavePart[s][k][2] + wavePart[s][k][3];
      int r = sR[s];
      if (k == 0) {
        double sc_ = v + (double)bcls[r];
        candKey[slot] = score_key64(sc_);
        candPack[slot] = ((u32)sIdx[s] << 13) | (u32)slot;
      } else {
        candDelta[(size_t)slot * 4 + (k - 1)] = v + (double)bbox[r * 4 + (k - 1)];
      }
    } else if (k == 0) {
      candKey[slot] = 0ULL;
      candPack[slot] = 0xFFFFFFFFu;
    }
  }
}

// ---------------- rank-by-count + fused decode: boxesD[rank] = decode(pack) -------
__global__ __launch_bounds__(256) void k_rank(const u64* __restrict__ candKey,
                                              const u32* __restrict__ candPack,
                                              const double* __restrict__ candDelta,
                                              double* __restrict__ boxesD) {
  __shared__ u64 fk[1024];
  __shared__ u32 fp[1024];
  __shared__ u32 rsum[32][8];
  int tid = threadIdx.x;
  int c = tid & 31;
  int g = tid >> 5;
  int ci = blockIdx.x * 32 + c;
  u64 mk = candKey[ci];
  u32 mp = candPack[ci];
  u32 cnt = 0;
  for (int chunk = 0; chunk < 8; ++chunk) {
    __syncthreads();
    for (int e = tid; e < 1024; e += 256) {
      fk[e] = candKey[chunk * 1024 + e];
      fp[e] = candPack[chunk * 1024 + e];
    }
    __syncthreads();
    int j0 = g * 128;
    #pragma unroll 4
    for (int j = j0; j < j0 + 128; ++j) {
      u64 kj = fk[j];
      cnt += (kj > mk || (kj == mk && fp[j] < mp)) ? 1u : 0u;
    }
  }
  rsum[c][g] = cnt;
  __syncthreads();
  if (tid < 32) {
    u32 rank = 0;
    #pragma unroll
    for (int q = 0; q < 8; ++q) rank += rsum[tid][q];
    if (rank < (u32)KTOP) {
      u32 pack = mp;
      u32 slot = pack & 0x1FFFu;
      u32 a = pack >> 13;
      int pix = (int)(a / 3u);
      int r = (int)(a - (u32)pix * 3u);
      int l, off;
      pix_level(pix, l, off);
      int W = 256 >> l;
      int idx = pix - off;
      int y = idx >> (8 - l);
      int x = idx & (W - 1);
      int sst = 4 << l;
      double ratio = (r == 0) ? 0.5 : (r == 1) ? 1.0 : 2.0;
      double wq = rint(sqrt((double)(sst * sst) / ratio));
      double hq = rint(wq * ratio);
      double Wa = wq * 8.0, Ha = hq * 8.0;
      double cx = (double)x * (double)sst + (double)(sst - 1) * 0.5;
      double cy = (double)y * (double)sst + (double)(sst - 1) * 0.5;
      double ax1 = (double)(float)(cx - 0.5 * (Wa - 1.0));
      double ay1 = (double)(float)(cy - 0.5 * (Ha - 1.0));
      double ax2 = (double)(float)(cx + 0.5 * (Wa - 1.0) + 1.0);
      double ay2 = (double)(float)(cy + 0.5 * (Ha - 1.0) + 1.0);
      double tx = candDelta[(size_t)slot * 4 + 0], tyv = candDelta[(size_t)slot * 4 + 1];
      double tw = candDelta[(size_t)slot * 4 + 2], th  = candDelta[(size_t)slot * 4 + 3];
      double wa = ax2 - ax1, ha = ay2 - ay1;
      double xa = (ax1 + ax2) * 0.5, ya = (ay1 + ay2) * 0.5;
      double clipv = (double)(float)log(1333.0 / 16.0);
      double wb = exp(fmin(tw, clipv)) * wa;
      double hb = exp(fmin(th, clipv)) * ha;
      double xb = tx * wa + xa;
      double yb = tyv * ha + ya;
      double bx1 = xb - 0.5 * wb, by1 = yb - 0.5 * hb;
      double bx2 = xb + 0.5 * wb, by2 = yb + 0.5 * hb;
      bx1 = fmin(fmax(bx1, 0.0), 1024.0);
      by1 = fmin(fmax(by1, 0.0), 1024.0);
      bx2 = fmin(fmax(bx2, 0.0), 1024.0);
      by2 = fmin(fmax(by2, 0.0), 1024.0);
      boxesD[(size_t)rank * 4 + 0] = bx1;
      boxesD[(size_t)rank * 4 + 1] = by1;
      boxesD[(size_t)rank * 4 + 2] = bx2;
      boxesD[(size_t)rank * 4 + 3] = by2;
    }
  }
}

// ---------------- NMS masks: upper-triangular row bitmask -------------------------
__global__ void k_mask(const double* __restrict__ boxesD, u64* __restrict__ maskA) {
  __shared__ double cbx[64][4];
  int lane = threadIdx.x;
  int bc = blockIdx.x, br = blockIdx.y;
  if (bc < br) return;
  int ci = bc * 64 + lane;
  if (ci < KTOP) {
    cbx[lane][0] = boxesD[(size_t)ci * 4 + 0];
    cbx[lane][1] = boxesD[(size_t)ci * 4 + 1];
    cbx[lane][2] = boxesD[(size_t)ci * 4 + 2];
    cbx[lane][3] = boxesD[(size_t)ci * 4 + 3];
  } else {
    cbx[lane][0] = -1e30; cbx[lane][1] = -1e30; cbx[lane][2] = -1e30; cbx[lane][3] = -1e30;
  }
  __syncthreads();
  int ri = br * 64 + lane;
  if (ri >= KTOP) return;
  double rx1 = boxesD[(size_t)ri * 4 + 0], ry1 = boxesD[(size_t)ri * 4 + 1];
  double rx2 = boxesD[(size_t)ri * 4 + 2], ry2 = boxesD[(size_t)ri * 4 + 3];
  double ra = (rx2 - rx1) * (ry2 - ry1);
  u64 bits = 0;
  #pragma unroll 4
  for (int j = 0; j < 64; ++j) {
    int cj = bc * 64 + j;
    double iw = fmin(rx2, cbx[j][2]) - fmax(rx1, cbx[j][0]);
    double ih = fmin(ry2, cbx[j][3]) - fmax(ry1, cbx[j][1]);
    iw = fmax(iw, 0.0); ih = fmax(ih, 0.0);
    double inter = iw * ih;
    double ca = (cbx[j][2] - cbx[j][0]) * (cbx[j][3] - cbx[j][1]);
    double iou = inter / (ra + ca - inter);
    if (cj > ri && iou > 0.7) bits |= (1ULL << j);
  }
  maskA[(size_t)ri * NWORDS + bc] = bits;
}

// ---------------- 16-wave greedy reduce: ctz-skip resolve, 1 barrier/chunk --------
__global__ __launch_bounds__(1024) void k_nms_reduce(const u64* __restrict__ maskA,
                                                     u32* __restrict__ keep) {
  __shared__ u64 rm[NWORDS];
  int tid = threadIdx.x;
  int wv = tid >> 6, lane = tid & 63;
  for (int i = tid; i < NWORDS; i += 1024) rm[i] = 0ULL;
  __syncthreads();
  u64 diagNext = maskA[(size_t)lane * NWORDS + 0];
  int keptTot = 0;
  for (int c = 0; c < NWORDS; ++c) {
    int rows = KTOP - c * 64; if (rows > 64) rows = 64;
    u64 validM = (rows == 64) ? ~0ULL : ((1ULL << rows) - 1ULL);
    size_t rowbase = (size_t)(c * 64 + lane) * NWORDS;
    bool lv = lane < rows;
    int w0i = c + wv;
    u64 v0 = (lv && w0i      < NWORDS) ? maskA[rowbase + w0i]      : 0ULL;
    u64 v1 = (lv && w0i + 16 < NWORDS) ? maskA[rowbase + w0i + 16] : 0ULL;
    u64 v2 = (lv && w0i + 32 < NWORDS) ? maskA[rowbase + w0i + 32] : 0ULL;
    u64 v3 = (lv && w0i + 48 < NWORDS) ? maskA[rowbase + w0i + 48] : 0ULL;
    u64 v4 = (lv && w0i + 64 < NWORDS) ? maskA[rowbase + w0i + 64] : 0ULL;
    u64 v5 = (lv && w0i + 80 < NWORDS) ? maskA[rowbase + w0i + 80] : 0ULL;
    u64 diag = diagNext;
    if (c + 1 < NWORDS) {
      int nrows = KTOP - (c + 1) * 64; if (nrows > 64) nrows = 64;
      diagNext = (lane < nrows) ? maskA[(size_t)((c + 1) * 64 + lane) * NWORDS + (c + 1)] : 0ULL;
    }
    u64 R = rm[c];
    u64 undec = (~R) & validM;
    u64 km = 0;
    while (undec) {
      int j = __builtin_ctzll(undec);
      km |= (1ULL << j);
      u64 dj = (u64)__shfl((unsigned long long)diag, j);
      undec &= ~(dj | (1ULL << j));
    }
    if (wv == 0 && lane < rows) keep[c * 64 + lane] = (u32)((km >> lane) & 1ULL);
    keptTot += (int)__popcll(km);
    if (keptTot >= 1000) {
      for (int i = (c + 1) * 64 + tid; i < KTOP; i += 1024) keep[i] = 0u;
      return;
    }
    u64 sel = ((km >> lane) & 1ULL) ? ~0ULL : 0ULL;
    v0 &= sel; v1 &= sel; v2 &= sel; v3 &= sel; v4 &= sel; v5 &= sel;
    #pragma unroll
    for (int s = 32; s; s >>= 1) {
      v0 |= (u64)__shfl_xor((unsigned long long)v0, s);
      v1 |= (u64)__shfl_xor((unsigned long long)v1, s);
      v2 |= (u64)__shfl_xor((unsigned long long)v2, s);
      v3 |= (u64)__shfl_xor((unsigned long long)v3, s);
      v4 |= (u64)__shfl_xor((unsigned long long)v4, s);
      v5 |= (u64)__shfl_xor((unsigned long long)v5, s);
    }
    if (lane == 0) {
      if (w0i      < NWORDS) rm[w0i]      |= v0;
      if (w0i + 16 < NWORDS) rm[w0i + 16] |= v1;
      if (w0i + 32 < NWORDS) rm[w0i + 32] |= v2;
      if (w0i + 48 < NWORDS) rm[w0i + 48] |= v3;
      if (w0i + 64 < NWORDS) rm[w0i + 64] |= v4;
      if (w0i + 80 < NWORDS) rm[w0i + 80] |= v5;
    }
    __syncthreads();
  }
}

// ---------------- emit first 1000 kept boxes (zeros after) ------------------------
__global__ __launch_bounds__(1024) void k_emit(const u32* __restrict__ keep,
                                               const double* __restrict__ boxesD,
                                               float* __restrict__ out) {
  __shared__ u32 partial[1024];
  __shared__ u32 excl[1024];
  int tid = threadIdx.x;
  for (int j = tid; j < 4000; j += 1024) out[j] = 0.f;
  int base = tid * 6;
  u32 kv[6];
  u32 c = 0;
  #pragma unroll
  for (int u = 0; u < 6; ++u) {
    int j = base + u;
    kv[u] = (j < KTOP) ? keep[j] : 0u;
    c += kv[u];
  }
  partial[tid] = c;
  __syncthreads();
  if (tid == 0) {
    u32 run = 0;
    for (int t = 0; t < 1024; ++t) { excl[t] = run; run += partial[t]; }
  }
  __syncthreads();
  u32 p = excl[tid];
  #pragma unroll
  for (int u = 0; u < 6; ++u) {
    int j = base + u;
    if (j < KTOP && kv[u]) {
      if (p < 1000u) {
        out[p * 4 + 0] = (float)boxesD[(size_t)j * 4 + 0];
        out[p * 4 + 1] = (float)boxesD[(size_t)j * 4 + 1];
        out[p * 4 + 2] = (float)boxesD[(size_t)j * 4 + 2];
        out[p * 4 + 3] = (float)boxesD[(size_t)j * 4 + 3];
      }
      ++p;
    }
  }
}

extern "C" void kernel_launch(void* const* d_in, const int* in_sizes, int n_in,
                              void* d_out, int out_size, void* d_ws, size_t ws_size,
                              hipStream_t stream) {
  const float* f0   = (const float*)d_in[1];
  const float* f1   = (const float*)d_in[2];
  const float* f2   = (const float*)d_in[3];
  const float* f3   = (const float*)d_in[4];
  const float* f4   = (const float*)d_in[5];
  const float* w0   = (const float*)d_in[6];
  const float* b0   = (const float*)d_in[7];
  const float* wcls = (const float*)d_in[8];
  const float* bcls = (const float*)d_in[9];
  const float* wbox = (const float*)d_in[10];
  const float* bbox = (const float*)d_in[11];
  float* out = (float*)d_out;
  char* ws = (char*)d_ws;

  size_t off = 0;
  auto alloc = [&](size_t bytes) { size_t o = off; off += (bytes + 255) & ~(size_t)255; return o; };
  size_t off_scr  = alloc((size_t)A_TOTAL * 4);
  size_t off_wt   = alloc((size_t)256 * 2304 * 8);
  size_t off_wk   = alloc((size_t)256 * 2304 * 2);
  size_t off_hp   = alloc((size_t)4 * PIXMAX * 256 * 8);
  size_t off_ci   = alloc((size_t)CANDMAX * 4);
  size_t off_ck   = alloc((size_t)CANDMAX * 8);
  size_t off_cp   = alloc((size_t)CANDMAX * 4);
  size_t off_cd   = alloc((size_t)CANDMAX * 4 * 8);
  size_t off_pl   = alloc((size_t)PIXMAX * 4);
  size_t off_pm   = alloc((size_t)NPIX * 4);
  size_t off_box  = alloc((size_t)KTOP * 4 * 8);
  size_t off_keep = alloc((size_t)KTOP * 4);
  size_t off_mask = alloc((size_t)KTOP * NWORDS * 8);
  size_t off_bcnt = alloc((size_t)1024 * 4);
  size_t off_boff = alloc((size_t)1024 * 4);
  size_t off_bcp  = alloc((size_t)1024 * 4);
  size_t off_bop  = alloc((size_t)1024 * 4);
  size_t off_bins = alloc((size_t)NBINS * 4);
  size_t off_sub  = alloc((size_t)256 * 4);
  size_t off_meta = alloc((size_t)64 * 4);
  size_t off_end  = off;
  (void)in_sizes; (void)n_in; (void)out_size; (void)ws_size;

  float*  scr       = (float*)(ws + off_scr);
  double* wt64      = (double*)(ws + off_wt);
  ushort* wkf       = (ushort*)(ws + off_wk);
  double* hpart     = (double*)(ws + off_hp);
  u32*    candIdx   = (u32*)(ws + off_ci);
  u64*    candKey   = (u64*)(ws + off_ck);
  u32*    candPack  = (u32*)(ws + off_cp);
  double* candDelta = (double*)(ws + off_cd);
  u32*    pixList   = (u32*)(ws + off_pl);
  u32*    pixMap    = (u32*)(ws + off_pm);
  double* boxesD    = (double*)(ws + off_box);
  u32*    keep      = (u32*)(ws + off_keep);
  u64*    maskA     = (u64*)(ws + off_mask);
  u32*    blkCnt    = (u32*)(ws + off_bcnt);
  u32*    blkOff    = (u32*)(ws + off_boff);
  u32*    blkCntP   = (u32*)(ws + off_bcp);
  u32*    blkOffP   = (u32*)(ws + off_bop);
  u32*    bins      = (u32*)(ws + off_bins);
  u32*    sub       = (u32*)(ws + off_sub);
  u32*    meta      = (u32*)(ws + off_meta);

  hipMemsetAsync(ws + off_bins, 0, off_end - off_bins, stream);

  k_prep_w<<<2304, 256, 0, stream>>>(w0, wt64, wkf);
  k_conv_mfma<<<1364, 256, 0, stream>>>(f0, f1, f2, f3, f4, wkf, b0, wcls, bcls, scr);
  k_hist1<<<64, 256, 0, stream>>>(scr, bins);
  k_scan1<<<1, 256, 0, stream>>>(bins, meta);
  k_hist2<<<1023, 256, 0, stream>>>(scr, meta, sub);
  k_scan2<<<1, 64, 0, stream>>>(sub, meta);
  k_cnt2<<<1023, 256, 0, stream>>>(scr, meta, blkCnt, blkCntP);
  k_scanblk2<<<1, 1024, 0, stream>>>(blkCnt, blkOff, meta + 1, blkCntP, blkOffP, meta + 4);
  k_fill2<<<1023, 256, 0, stream>>>(scr, meta, blkOff, blkOffP, candIdx, pixList, pixMap);
  k_hidden<<<(PIXMAX / 16) * 4, 256, 0, stream>>>(f0, f1, f2, f3, f4, wt64, pixList, meta, hpart);
  k_heads<<<CANDMAX / 8, 256, 0, stream>>>(wcls, bcls, wbox, bbox, b0, candIdx, pixMap, meta,
                                           hpart, candKey, candPack, candDelta);
  k_rank<<<CANDMAX / 32, 256, 0, stream>>>(candKey, candPack, candDelta, boxesD);
  k_mask<<<dim3(NWORDS, NWORDS), 64, 0, stream>>>(boxesD, maskA);
  k_nms_reduce<<<1, 1024, 0, stream>>>(maskA, keep);
  k_emit<<<1, 1024, 0, stream>>>(keep, boxesD, out);
}

// Round 19
// 806.037 us; speedup vs baseline: 1.1190x; 1.1190x over previous
//
#include <hip/hip_runtime.h>
#include <cstdint>

typedef unsigned long long u64;
typedef unsigned int u32;
typedef unsigned short ushort;
typedef __attribute__((ext_vector_type(8))) short short8;
typedef __attribute__((ext_vector_type(4))) float f32x4;

#define A_TOTAL 261888   // 3 * 87296 anchors
#define NPIX    87296
#define KTOP    6000
#define KTARGET 7800     // screen candidate target (slack for bf16 screen error)
#define NWORDS  94       // ceil(6000/64)
#define CANDMAX 8192
#define PIXMAX  8192
#define NBINS   16384    // 14-bit fp32-key bins

__device__ __forceinline__ u64 score_key64(double s) {
  u64 u = (u64)__double_as_longlong(s);
  return (u & 0x8000000000000000ULL) ? ~u : (u | 0x8000000000000000ULL);
}
__device__ __forceinline__ u32 key32(float s) {
  u32 u = __float_as_uint(s);
  return (u & 0x80000000u) ? ~u : (u | 0x80000000u);
}
__device__ __forceinline__ ushort f2bf(float f) {   // RNE fp32->bf16 (finite inputs)
  u32 u = __float_as_uint(f);
  u32 r = (u + 0x7FFFu + ((u >> 16) & 1u)) >> 16;
  return (ushort)r;
}
__device__ __forceinline__ void pix_level(int pix, int& l, int& off) {
  if (pix < 65536)      { l = 0; off = 0; }
  else if (pix < 81920) { l = 1; off = 65536; }
  else if (pix < 86016) { l = 2; off = 81920; }
  else if (pix < 87040) { l = 3; off = 86016; }
  else                  { l = 4; off = 87040; }
}

// ---------------- weight prep: wt64 fp64 [k][oc] (exact fp32 values) + wkf bf16 ---
__global__ void k_prep_w(const float* __restrict__ w0, double* __restrict__ wt64,
                         ushort* __restrict__ wkf) {
  int i = blockIdx.x * 256 + threadIdx.x;
  if (i < 256 * 2304) {
    int o = i & 255;
    int ictap = i >> 8;
    float v = w0[o * 2304 + ictap];
    wt64[(size_t)ictap * 256 + o] = (double)v;
    int ic = ictap / 9;
    int tap = ictap - ic * 9;
    int w = o >> 6, mt = (o >> 4) & 3, l15 = o & 15;
    int ch = ic >> 5, kk = ic & 31;
    int l4 = kk >> 3, e = kk & 7;
    int lane = l4 * 16 + l15;
    wkf[((((w * 4 + mt) * 8 + ch) * 9 + tap) << 9) + lane * 8 + e] = f2bf(v);
  }
}

// ---------------- MFMA bf16 screening conv (round-14 structure) -------------------
__global__ __launch_bounds__(256, 2) void k_conv_mfma(
    const float* __restrict__ f0, const float* __restrict__ f1,
    const float* __restrict__ f2, const float* __restrict__ f3,
    const float* __restrict__ f4,
    const ushort* __restrict__ wkf, const float* __restrict__ b0,
    const float* __restrict__ wcls, const float* __restrict__ bcls,
    float* __restrict__ scr)
{
  __shared__ ushort xsl[100][40];        // [halo sp][32 ic +8 pad]  8.0 KB
  __shared__ float  part[3][64][17];     // head partials           13.1 KB

  int b = blockIdx.x;
  int l, tb;
  if (b < 1024)      { l = 0; tb = b; }
  else if (b < 1280) { l = 1; tb = b - 1024; }
  else if (b < 1344) { l = 2; tb = b - 1280; }
  else if (b < 1360) { l = 3; tb = b - 1344; }
  else               { l = 4; tb = b - 1360; }
  const float* feat = (l == 0) ? f0 : (l == 1) ? f1 : (l == 2) ? f2 : (l == 3) ? f3 : f4;
  int Hh = 256 >> l;
  int HW = Hh * Hh;
  int pixOff = (l == 0) ? 0 : (l == 1) ? 65536 : (l == 2) ? 81920 : (l == 3) ? 86016 : 87040;
  int shl = 5 - l;
  int ty = (tb >> shl) << 3;
  int tx = (tb & ((1 << shl) - 1)) << 3;

  int tid = threadIdx.x;
  int w = tid >> 6;
  int lane = tid & 63;
  int l15 = lane & 15;
  int l4 = lane >> 4;

  f32x4 zz = {0.f, 0.f, 0.f, 0.f};
  f32x4 acc[4][4];
  #pragma unroll
  for (int mt = 0; mt < 4; ++mt)
    #pragma unroll
    for (int tt = 0; tt < 4; ++tt) acc[mt][tt] = zz;

  for (int ch = 0; ch < 8; ++ch) {
    __syncthreads();
    for (int e = tid; e < 3200; e += 256) {
      int icl = e / 100;
      int sp = e - icl * 100;
      int yy = sp / 10;
      int xx = sp - yy * 10;
      int gy = ty + yy - 1, gx = tx + xx - 1;
      float v = 0.f;
      if (gy >= 0 && gy < Hh && gx >= 0 && gx < Hh)
        v = feat[(ch * 32 + icl) * HW + gy * Hh + gx];
      xsl[sp][icl] = f2bf(v);
    }
    __syncthreads();
    #pragma unroll
    for (int tap = 0; tap < 9; ++tap) {
      int dy = tap / 3;
      int dx = tap - dy * 3;
      short8 af[4], bf[4];
      #pragma unroll
      for (int mt = 0; mt < 4; ++mt) {
        int abase = ((((w * 4 + mt) * 8 + ch) * 9 + tap) << 9) + (lane << 3);
        af[mt] = *(const short8*)(wkf + abase);
      }
      #pragma unroll
      for (int tt = 0; tt < 4; ++tt) {
        int p = (tt << 4) + l15;
        int sp = ((p >> 3) + dy) * 10 + (p & 7) + dx;
        bf[tt] = *(const short8*)&xsl[sp][l4 << 3];
      }
      #pragma unroll
      for (int mt = 0; mt < 4; ++mt)
        #pragma unroll
        for (int tt = 0; tt < 4; ++tt)
          acc[mt][tt] = __builtin_amdgcn_mfma_f32_16x16x32_bf16(af[mt], bf[tt], acc[mt][tt], 0, 0, 0);
    }
  }

  float pr[3][4];
  #pragma unroll
  for (int kk = 0; kk < 3; ++kk)
    #pragma unroll
    for (int tt = 0; tt < 4; ++tt) pr[kk][tt] = 0.f;
  #pragma unroll
  for (int mt = 0; mt < 4; ++mt) {
    #pragma unroll
    for (int r = 0; r < 4; ++r) {
      int oc = (w << 6) + (mt << 4) + (l4 << 2) + r;
      float bb = b0[oc];
      float c0 = wcls[oc], c1 = wcls[256 + oc], c2 = wcls[512 + oc];
      #pragma unroll
      for (int tt = 0; tt < 4; ++tt) {
        float v = acc[mt][tt][r] + bb;
        v = v > 0.f ? v : 0.f;
        pr[0][tt] = fmaf(c0, v, pr[0][tt]);
        pr[1][tt] = fmaf(c1, v, pr[1][tt]);
        pr[2][tt] = fmaf(c2, v, pr[2][tt]);
      }
    }
  }
  __syncthreads();
  #pragma unroll
  for (int kk = 0; kk < 3; ++kk)
    #pragma unroll
    for (int tt = 0; tt < 4; ++tt)
      part[kk][(tt << 4) + l15][(w << 2) + l4] = pr[kk][tt];
  __syncthreads();
  if (tid < 192) {
    int kk = tid >> 6;
    int px = tid & 63;
    float s = 0.f;
    #pragma unroll
    for (int q = 0; q < 16; ++q) s += part[kk][px][q];
    int pix = pixOff + (ty + (px >> 3)) * Hh + (tx + (px & 7));
    scr[pix * 3 + kk] = s + bcls[kk];
  }
}

// ---------------- exact two-level threshold selection (count-targeted) ------------
__global__ void k_hist1(const float* __restrict__ scr, u32* __restrict__ bins) {
  __shared__ u32 h[NBINS];
  int tid = threadIdx.x;
  for (int idx = tid; idx < NBINS; idx += 256) h[idx] = 0;
  __syncthreads();
  for (int i = blockIdx.x * 256 + tid; i < A_TOTAL; i += gridDim.x * 256)
    atomicAdd(&h[key32(scr[i]) >> 18], 1u);
  __syncthreads();
  for (int idx = tid; idx < NBINS; idx += 256) {
    u32 v = h[idx];
    if (v) atomicAdd(&bins[idx], v);
  }
}

__global__ void k_scan1(const u32* __restrict__ bins, u32* __restrict__ meta) {
  __shared__ u32 psum[256];
  int tid = threadIdx.x;
  u32 s = 0;
  for (int u = 0; u < 64; ++u) s += bins[tid * 64 + u];
  psum[tid] = s;
  __syncthreads();
  if (tid == 0) {
    u32 run = 0;
    for (int t = 255; t >= 0; --t) { u32 tmp = psum[t]; psum[t] = run; run += tmp; }
  }
  __syncthreads();
  u32 cum = psum[tid];
  if (cum < (u32)KTARGET) {
    for (int u = 63; u >= 0; --u) {
      u32 bv = bins[tid * 64 + u];
      u32 nc = cum + bv;
      if (nc >= (u32)KTARGET) {
        meta[0] = (u32)(tid * 64 + u);
        meta[2] = cum;
        break;
      }
      cum = nc;
    }
  }
}

__global__ void k_hist2(const float* __restrict__ scr, const u32* __restrict__ meta,
                        u32* __restrict__ sub) {
  int i = blockIdx.x * 256 + threadIdx.x;
  if (i < A_TOTAL) {
    u32 k = key32(scr[i]);
    if ((k >> 18) == meta[0]) atomicAdd(&sub[(k >> 10) & 0xFFu], 1u);
  }
}

__global__ void k_scan2(const u32* __restrict__ sub, u32* __restrict__ meta) {
  if (threadIdx.x == 0) {
    u32 b = meta[0];
    u32 c = meta[2];
    u32 T = b << 18;
    for (int u = 255; u >= 0; --u) {
      c += sub[u];
      if (c >= (u32)KTARGET) { T = (b << 18) | ((u32)u << 10); break; }
    }
    meta[3] = (T >= (2u << 10)) ? (T - (2u << 10)) : 0u;
  }
}

// ---------------- fused ordered compaction: anchors + pixels ----------------------
__global__ void k_cnt2(const float* __restrict__ scr, const u32* __restrict__ meta,
                       u32* __restrict__ blkCnt, u32* __restrict__ blkCntP) {
  __shared__ u32 wc[4], wcp[4];
  int tid = threadIdx.x;
  int lane = tid & 63, wv = tid >> 6;
  u32 T = meta[3];
  int i = blockIdx.x * 256 + tid;
  bool qa = (i < A_TOTAL) && (key32(scr[i]) >= T);
  u64 ba = __ballot(qa);
  bool qp = false;
  if (i < NPIX)
    qp = (key32(scr[i * 3 + 0]) >= T) || (key32(scr[i * 3 + 1]) >= T) || (key32(scr[i * 3 + 2]) >= T);
  u64 bp = __ballot(qp);
  if (lane == 0) { wc[wv] = (u32)__popcll(ba); wcp[wv] = (u32)__popcll(bp); }
  __syncthreads();
  if (tid == 0) {
    blkCnt[blockIdx.x]  = wc[0] + wc[1] + wc[2] + wc[3];
    blkCntP[blockIdx.x] = wcp[0] + wcp[1] + wcp[2] + wcp[3];
  }
}

__global__ __launch_bounds__(1024) void k_scanblk2(const u32* __restrict__ blkCnt,
                                                   u32* __restrict__ blkOff,
                                                   u32* __restrict__ totA,
                                                   const u32* __restrict__ blkCntP,
                                                   u32* __restrict__ blkOffP,
                                                   u32* __restrict__ totP) {
  __shared__ u32 buf[2][1024];
  int tid = threadIdx.x;
  for (int pass = 0; pass < 2; ++pass) {
    const u32* src_ = pass ? blkCntP : blkCnt;
    u32* dst_ = pass ? blkOffP : blkOff;
    u32* tot_ = pass ? totP : totA;
    u32 v = (tid < 1023) ? src_[tid] : 0u;
    buf[0][tid] = v;
    __syncthreads();
    int src = 0;
    for (int d = 1; d < 1024; d <<= 1) {
      u32 t = buf[src][tid] + ((tid >= d) ? buf[src][tid - d] : 0u);
      buf[src ^ 1][tid] = t;
      src ^= 1;
      __syncthreads();
    }
    if (tid < 1023) dst_[tid] = buf[src][tid] - v;
    if (tid == 0) tot_[0] = buf[src][1022];
    __syncthreads();
  }
}

__global__ void k_fill2(const float* __restrict__ scr, const u32* __restrict__ meta,
                        const u32* __restrict__ blkOff, const u32* __restrict__ blkOffP,
                        u32* __restrict__ candIdx, u32* __restrict__ pixList,
                        u32* __restrict__ pixMap) {
  __shared__ u32 wbase[4], wbaseP[4];
  int tid = threadIdx.x;
  int lane = tid & 63, wv = tid >> 6;
  u32 T = meta[3];
  int i = blockIdx.x * 256 + tid;
  bool qa = (i < A_TOTAL) && (key32(scr[i]) >= T);
  u64 ba = __ballot(qa);
  bool qp = false;
  if (i < NPIX)
    qp = (key32(scr[i * 3 + 0]) >= T) || (key32(scr[i * 3 + 1]) >= T) || (key32(scr[i * 3 + 2]) >= T);
  u64 bp = __ballot(qp);
  if (lane == 0) { wbase[wv] = (u32)__popcll(ba); wbaseP[wv] = (u32)__popcll(bp); }
  __syncthreads();
  if (tid == 0) {
    u32 r = blkOff[blockIdx.x];
    #pragma unroll
    for (int w2 = 0; w2 < 4; ++w2) { u32 t = wbase[w2]; wbase[w2] = r; r += t; }
    u32 rp = blkOffP[blockIdx.x];
    #pragma unroll
    for (int w2 = 0; w2 < 4; ++w2) { u32 t = wbaseP[w2]; wbaseP[w2] = rp; rp += t; }
  }
  __syncthreads();
  if (qa) {
    u32 rank = (u32)__popcll(ba & ((1ULL << lane) - 1ULL));
    u32 pos = wbase[wv] + rank;
    if (pos < CANDMAX) candIdx[pos] = (u32)i;
  }
  if (qp) {
    u32 rank = (u32)__popcll(bp & ((1ULL << lane) - 1ULL));
    u32 pos = wbaseP[wv] + rank;
    if (pos < PIXMAX) { pixList[pos] = (u32)i; pixMap[i] = pos; }
  }
}

// ---------------- exact fp64 hidden: 32 px/block (2x arithmetic intensity) --------
// L2-BW-bound fix: same 2KB weight row now feeds 4oc x 8px per thread (32 FMA/k).
// Weight L2 traffic halves vs 16px/block. kc-major keeps each 1.18MB quarter
// L2-resident. FMA order per (pixel,oc,kc) unchanged -> bit-identical output.
#define KCH 144
__global__ __launch_bounds__(256, 4) void k_hidden(
    const float* __restrict__ f0, const float* __restrict__ f1,
    const float* __restrict__ f2, const float* __restrict__ f3,
    const float* __restrict__ f4,
    const double* __restrict__ wt64,
    const u32* __restrict__ pixList, const u32* __restrict__ meta,
    double* __restrict__ hpart)
{
  __shared__ double patch[KCH][32];       // 36.9 KB
  __shared__ int sValid[32], sY[32], sX[32], sW[32], sL[32];

  int tid = threadIdx.x;
  int pixblk = blockIdx.x & 255;          // PIXMAX/32 - 1
  int kc = blockIdx.x >> 8;
  int base = pixblk * 32;
  u32 np = meta[4];
  if (np > PIXMAX) np = PIXMAX;
  if (base >= (int)np) return;

  if (tid < 32) {
    int slot = base + tid;
    int v = slot < (int)np;
    sValid[tid] = v;
    int pix = v ? (int)pixList[slot] : 0;
    int l, off;
    pix_level(pix, l, off);
    int W = 256 >> l;
    int idx = pix - off;
    sL[tid] = l;
    sW[tid] = W;
    sY[tid] = idx >> (8 - l);
    sX[tid] = idx & (W - 1);
  }
  __syncthreads();

  // chunk cb covers ic range [cb*16, cb*16+16), k = ic*9 + tap
  auto stage = [&](int cb) {
    for (int t = tid; t < 1536; t += 256) {
      int s = t & 31;
      int rem = t >> 5;                   // 0..47 = icl*3 + dy
      int icl = rem / 3;
      int dy = rem - icl * 3;
      int ic = cb * 16 + icl;
      float v0 = 0.f, v1 = 0.f, v2 = 0.f;
      if (sValid[s]) {
        int l = sL[s], W = sW[s], y = sY[s], x = sX[s];
        const float* feat = (l == 0) ? f0 : (l == 1) ? f1 : (l == 2) ? f2 : (l == 3) ? f3 : f4;
        int gy = y + dy - 1;
        if (gy >= 0 && gy < W) {
          const float* rowp = feat + ic * W * W + gy * W;
          if (x - 1 >= 0) v0 = rowp[x - 1];
          v1 = rowp[x];
          if (x + 1 < W) v2 = rowp[x + 1];
        }
      }
      int kb = icl * 9 + dy * 3;
      patch[kb + 0][s] = (double)v0;      // widen once at staging
      patch[kb + 1][s] = (double)v1;
      patch[kb + 2][s] = (double)v2;
    }
  };

  int ocq = tid & 63;                     // oc quad: oc = ocq*4 .. +3
  int pxq = tid >> 6;                     // px octet (wave-uniform): px = pxq*8..+7

  double acc[4][8];
  #pragma unroll
  for (int a = 0; a < 4; ++a)
    #pragma unroll
    for (int j = 0; j < 8; ++j) acc[a][j] = 0.0;

  int cb0 = kc * 4;                       // 16 chunks total, 4 per kc
  for (int i = 0; i < 4; ++i) {
    int cb = cb0 + i;
    if (i) __syncthreads();               // prior chunk's patch reads done
    stage(cb);
    __syncthreads();                      // staging visible
    const double* wb_ = wt64 + (size_t)(cb * KCH) * 256 + (ocq << 2);
    for (int kk = 0; kk < KCH; ++kk) {
      const double* pp = &patch[kk][pxq << 3];       // broadcast (4x ds_read_b128)
      double pd[8];
      #pragma unroll
      for (int j = 0; j < 8; ++j) pd[j] = pp[j];
      const double* wr = wb_ + (size_t)kk * 256;     // coalesced 2KB/wave
      double w_[4];
      #pragma unroll
      for (int a = 0; a < 4; ++a) w_[a] = wr[a];
      #pragma unroll
      for (int a = 0; a < 4; ++a)
        #pragma unroll
        for (int j = 0; j < 8; ++j)
          acc[a][j] = fma(w_[a], pd[j], acc[a][j]);
    }
  }

  #pragma unroll
  for (int j = 0; j < 8; ++j) {
    int s = (pxq << 3) + j;
    if (sValid[s]) {
      double* dst = &hpart[((size_t)kc * PIXMAX + base + s) * 256 + (ocq << 2)];
      dst[0] = acc[0][j];
      dst[1] = acc[1][j];
      dst[2] = acc[2][j];
      dst[3] = acc[3][j];
    }
  }
}

// ---------------- exact fp64 heads per candidate anchor (combines K-partials) -----
__global__ __launch_bounds__(256, 4) void k_heads(
    const float* __restrict__ wcls, const float* __restrict__ bcls,
    const float* __restrict__ wbox, const float* __restrict__ bbox,
    const float* __restrict__ b0,
    const u32* __restrict__ candIdx, const u32* __restrict__ pixMap,
    const u32* __restrict__ meta, const double* __restrict__ hpart,
    u64* __restrict__ candKey, u32* __restrict__ candPack, double* __restrict__ candDelta)
{
  __shared__ double wavePart[8][5][4];
  __shared__ int sIdx[8], sValid[8], sR[8], sPS[8];
  int tid = threadIdx.x;
  int lane = tid & 63;
  int wv = tid >> 6;
  int base = blockIdx.x * 8;
  u32 cnt = meta[1];
  if (cnt > CANDMAX) cnt = CANDMAX;

  if (base >= (int)cnt) {
    if (tid < 8) {
      candKey[base + tid] = 0ULL;
      candPack[base + tid] = 0xFFFFFFFFu;
    }
    return;
  }

  if (tid < 8) {
    int slot = base + tid;
    int v = slot < (int)cnt;
    sValid[tid] = v;
    int aidx = v ? (int)candIdx[slot] : 0;
    sIdx[tid] = aidx;
    int pix = aidx / 3;
    sR[tid] = aidx - pix * 3;
    sPS[tid] = v ? (int)pixMap[pix] : 0;
  }
  __syncthreads();

  double bb = (double)b0[tid];
  for (int s = 0; s < 8; ++s) {
    if (!sValid[s]) continue;
    int r = sR[s];
    size_t ps = (size_t)sPS[s];
    double hv = hpart[ps * 256 + tid];
    hv = hv + hpart[((size_t)PIXMAX + ps) * 256 + tid];
    hv = hv + hpart[((size_t)2 * PIXMAX + ps) * 256 + tid];
    hv = hv + hpart[((size_t)3 * PIXMAX + ps) * 256 + tid];
    hv = hv + bb;
    hv = hv > 0.0 ? hv : 0.0;
    double p0 = (double)wcls[r * 256 + tid] * hv;
    double p1 = (double)wbox[(r * 4 + 0) * 256 + tid] * hv;
    double p2 = (double)wbox[(r * 4 + 1) * 256 + tid] * hv;
    double p3 = (double)wbox[(r * 4 + 2) * 256 + tid] * hv;
    double p4 = (double)wbox[(r * 4 + 3) * 256 + tid] * hv;
    #pragma unroll
    for (int d = 32; d; d >>= 1) {
      p0 += __shfl_xor(p0, d);
      p1 += __shfl_xor(p1, d);
      p2 += __shfl_xor(p2, d);
      p3 += __shfl_xor(p3, d);
      p4 += __shfl_xor(p4, d);
    }
    if (lane == 0) {
      wavePart[s][0][wv] = p0;
      wavePart[s][1][wv] = p1;
      wavePart[s][2][wv] = p2;
      wavePart[s][3][wv] = p3;
      wavePart[s][4][wv] = p4;
    }
  }
  __syncthreads();
  if (tid < 40) {
    int s = tid / 5;
    int k = tid - s * 5;
    int slot = base + s;
    if (sValid[s]) {
      double v = wavePart[s][k][0] + wavePart[s][k][1] + wavePart[s][k][2] + wavePart[s][k][3];
      int r = sR[s];
      if (k == 0) {
        double sc_ = v + (double)bcls[r];
        candKey[slot] = score_key64(sc_);
        candPack[slot] = ((u32)sIdx[s] << 13) | (u32)slot;
      } else {
        candDelta[(size_t)slot * 4 + (k - 1)] = v + (double)bbox[r * 4 + (k - 1)];
      }
    } else if (k == 0) {
      candKey[slot] = 0ULL;
      candPack[slot] = 0xFFFFFFFFu;
    }
  }
}

// ---------------- rank-by-count + fused decode: boxesD[rank] = decode(pack) -------
__global__ __launch_bounds__(256) void k_rank(const u64* __restrict__ candKey,
                                              const u32* __restrict__ candPack,
                                              const double* __restrict__ candDelta,
                                              double* __restrict__ boxesD) {
  __shared__ u64 fk[1024];
  __shared__ u32 fp[1024];
  __shared__ u32 rsum[32][8];
  int tid = threadIdx.x;
  int c = tid & 31;
  int g = tid >> 5;
  int ci = blockIdx.x * 32 + c;
  u64 mk = candKey[ci];
  u32 mp = candPack[ci];
  u32 cnt = 0;
  for (int chunk = 0; chunk < 8; ++chunk) {
    __syncthreads();
    for (int e = tid; e < 1024; e += 256) {
      fk[e] = candKey[chunk * 1024 + e];
      fp[e] = candPack[chunk * 1024 + e];
    }
    __syncthreads();
    int j0 = g * 128;
    #pragma unroll 4
    for (int j = j0; j < j0 + 128; ++j) {
      u64 kj = fk[j];
      cnt += (kj > mk || (kj == mk && fp[j] < mp)) ? 1u : 0u;
    }
  }
  rsum[c][g] = cnt;
  __syncthreads();
  if (tid < 32) {
    u32 rank = 0;
    #pragma unroll
    for (int q = 0; q < 8; ++q) rank += rsum[tid][q];
    if (rank < (u32)KTOP) {
      u32 pack = mp;
      u32 slot = pack & 0x1FFFu;
      u32 a = pack >> 13;
      int pix = (int)(a / 3u);
      int r = (int)(a - (u32)pix * 3u);
      int l, off;
      pix_level(pix, l, off);
      int W = 256 >> l;
      int idx = pix - off;
      int y = idx >> (8 - l);
      int x = idx & (W - 1);
      int sst = 4 << l;
      double ratio = (r == 0) ? 0.5 : (r == 1) ? 1.0 : 2.0;
      double wq = rint(sqrt((double)(sst * sst) / ratio));
      double hq = rint(wq * ratio);
      double Wa = wq * 8.0, Ha = hq * 8.0;
      double cx = (double)x * (double)sst + (double)(sst - 1) * 0.5;
      double cy = (double)y * (double)sst + (double)(sst - 1) * 0.5;
      double ax1 = (double)(float)(cx - 0.5 * (Wa - 1.0));
      double ay1 = (double)(float)(cy - 0.5 * (Ha - 1.0));
      double ax2 = (double)(float)(cx + 0.5 * (Wa - 1.0) + 1.0);
      double ay2 = (double)(float)(cy + 0.5 * (Ha - 1.0) + 1.0);
      double tx = candDelta[(size_t)slot * 4 + 0], tyv = candDelta[(size_t)slot * 4 + 1];
      double tw = candDelta[(size_t)slot * 4 + 2], th  = candDelta[(size_t)slot * 4 + 3];
      double wa = ax2 - ax1, ha = ay2 - ay1;
      double xa = (ax1 + ax2) * 0.5, ya = (ay1 + ay2) * 0.5;
      double clipv = (double)(float)log(1333.0 / 16.0);
      double wb = exp(fmin(tw, clipv)) * wa;
      double hb = exp(fmin(th, clipv)) * ha;
      double xb = tx * wa + xa;
      double yb = tyv * ha + ya;
      double bx1 = xb - 0.5 * wb, by1 = yb - 0.5 * hb;
      double bx2 = xb + 0.5 * wb, by2 = yb + 0.5 * hb;
      bx1 = fmin(fmax(bx1, 0.0), 1024.0);
      by1 = fmin(fmax(by1, 0.0), 1024.0);
      bx2 = fmin(fmax(bx2, 0.0), 1024.0);
      by2 = fmin(fmax(by2, 0.0), 1024.0);
      boxesD[(size_t)rank * 4 + 0] = bx1;
      boxesD[(size_t)rank * 4 + 1] = by1;
      boxesD[(size_t)rank * 4 + 2] = bx2;
      boxesD[(size_t)rank * 4 + 3] = by2;
    }
  }
}

// ---------------- NMS masks: upper-triangular row bitmask -------------------------
__global__ void k_mask(const double* __restrict__ boxesD, u64* __restrict__ maskA) {
  __shared__ double cbx[64][4];
  int lane = threadIdx.x;
  int bc = blockIdx.x, br = blockIdx.y;
  if (bc < br) return;
  int ci = bc * 64 + lane;
  if (ci < KTOP) {
    cbx[lane][0] = boxesD[(size_t)ci * 4 + 0];
    cbx[lane][1] = boxesD[(size_t)ci * 4 + 1];
    cbx[lane][2] = boxesD[(size_t)ci * 4 + 2];
    cbx[lane][3] = boxesD[(size_t)ci * 4 + 3];
  } else {
    cbx[lane][0] = -1e30; cbx[lane][1] = -1e30; cbx[lane][2] = -1e30; cbx[lane][3] = -1e30;
  }
  __syncthreads();
  int ri = br * 64 + lane;
  if (ri >= KTOP) return;
  double rx1 = boxesD[(size_t)ri * 4 + 0], ry1 = boxesD[(size_t)ri * 4 + 1];
  double rx2 = boxesD[(size_t)ri * 4 + 2], ry2 = boxesD[(size_t)ri * 4 + 3];
  double ra = (rx2 - rx1) * (ry2 - ry1);
  u64 bits = 0;
  #pragma unroll 4
  for (int j = 0; j < 64; ++j) {
    int cj = bc * 64 + j;
    double iw = fmin(rx2, cbx[j][2]) - fmax(rx1, cbx[j][0]);
    double ih = fmin(ry2, cbx[j][3]) - fmax(ry1, cbx[j][1]);
    iw = fmax(iw, 0.0); ih = fmax(ih, 0.0);
    double inter = iw * ih;
    double ca = (cbx[j][2] - cbx[j][0]) * (cbx[j][3] - cbx[j][1]);
    double iou = inter / (ra + ca - inter);
    if (cj > ri && iou > 0.7) bits |= (1ULL << j);
  }
  maskA[(size_t)ri * NWORDS + bc] = bits;
}

// ---------------- 16-wave greedy reduce: ctz-skip resolve, 1 barrier/chunk --------
__global__ __launch_bounds__(1024) void k_nms_reduce(const u64* __restrict__ maskA,
                                                     u32* __restrict__ keep) {
  __shared__ u64 rm[NWORDS];
  int tid = threadIdx.x;
  int wv = tid >> 6, lane = tid & 63;
  for (int i = tid; i < NWORDS; i += 1024) rm[i] = 0ULL;
  __syncthreads();
  u64 diagNext = maskA[(size_t)lane * NWORDS + 0];
  int keptTot = 0;
  for (int c = 0; c < NWORDS; ++c) {
    int rows = KTOP - c * 64; if (rows > 64) rows = 64;
    u64 validM = (rows == 64) ? ~0ULL : ((1ULL << rows) - 1ULL);
    size_t rowbase = (size_t)(c * 64 + lane) * NWORDS;
    bool lv = lane < rows;
    int w0i = c + wv;
    u64 v0 = (lv && w0i      < NWORDS) ? maskA[rowbase + w0i]      : 0ULL;
    u64 v1 = (lv && w0i + 16 < NWORDS) ? maskA[rowbase + w0i + 16] : 0ULL;
    u64 v2 = (lv && w0i + 32 < NWORDS) ? maskA[rowbase + w0i + 32] : 0ULL;
    u64 v3 = (lv && w0i + 48 < NWORDS) ? maskA[rowbase + w0i + 48] : 0ULL;
    u64 v4 = (lv && w0i + 64 < NWORDS) ? maskA[rowbase + w0i + 64] : 0ULL;
    u64 v5 = (lv && w0i + 80 < NWORDS) ? maskA[rowbase + w0i + 80] : 0ULL;
    u64 diag = diagNext;
    if (c + 1 < NWORDS) {
      int nrows = KTOP - (c + 1) * 64; if (nrows > 64) nrows = 64;
      diagNext = (lane < nrows) ? maskA[(size_t)((c + 1) * 64 + lane) * NWORDS + (c + 1)] : 0ULL;
    }
    u64 R = rm[c];
    u64 undec = (~R) & validM;
    u64 km = 0;
    while (undec) {
      int j = __builtin_ctzll(undec);
      km |= (1ULL << j);
      u64 dj = (u64)__shfl((unsigned long long)diag, j);
      undec &= ~(dj | (1ULL << j));
    }
    if (wv == 0 && lane < rows) keep[c * 64 + lane] = (u32)((km >> lane) & 1ULL);
    keptTot += (int)__popcll(km);
    if (keptTot >= 1000) {
      for (int i = (c + 1) * 64 + tid; i < KTOP; i += 1024) keep[i] = 0u;
      return;
    }
    u64 sel = ((km >> lane) & 1ULL) ? ~0ULL : 0ULL;
    v0 &= sel; v1 &= sel; v2 &= sel; v3 &= sel; v4 &= sel; v5 &= sel;
    #pragma unroll
    for (int s = 32; s; s >>= 1) {
      v0 |= (u64)__shfl_xor((unsigned long long)v0, s);
      v1 |= (u64)__shfl_xor((unsigned long long)v1, s);
      v2 |= (u64)__shfl_xor((unsigned long long)v2, s);
      v3 |= (u64)__shfl_xor((unsigned long long)v3, s);
      v4 |= (u64)__shfl_xor((unsigned long long)v4, s);
      v5 |= (u64)__shfl_xor((unsigned long long)v5, s);
    }
    if (lane == 0) {
      if (w0i      < NWORDS) rm[w0i]      |= v0;
      if (w0i + 16 < NWORDS) rm[w0i + 16] |= v1;
      if (w0i + 32 < NWORDS) rm[w0i + 32] |= v2;
      if (w0i + 48 < NWORDS) rm[w0i + 48] |= v3;
      if (w0i + 64 < NWORDS) rm[w0i + 64] |= v4;
      if (w0i + 80 < NWORDS) rm[w0i + 80] |= v5;
    }
    __syncthreads();
  }
}

// ---------------- emit first 1000 kept boxes (zeros after) ------------------------
__global__ __launch_bounds__(1024) void k_emit(const u32* __restrict__ keep,
                                               const double* __restrict__ boxesD,
                                               float* __restrict__ out) {
  __shared__ u32 partial[1024];
  __shared__ u32 excl[1024];
  int tid = threadIdx.x;
  for (int j = tid; j < 4000; j += 1024) out[j] = 0.f;
  int base = tid * 6;
  u32 kv[6];
  u32 c = 0;
  #pragma unroll
  for (int u = 0; u < 6; ++u) {
    int j = base + u;
    kv[u] = (j < KTOP) ? keep[j] : 0u;
    c += kv[u];
  }
  partial[tid] = c;
  __syncthreads();
  if (tid == 0) {
    u32 run = 0;
    for (int t = 0; t < 1024; ++t) { excl[t] = run; run += partial[t]; }
  }
  __syncthreads();
  u32 p = excl[tid];
  #pragma unroll
  for (int u = 0; u < 6; ++u) {
    int j = base + u;
    if (j < KTOP && kv[u]) {
      if (p < 1000u) {
        out[p * 4 + 0] = (float)boxesD[(size_t)j * 4 + 0];
        out[p * 4 + 1] = (float)boxesD[(size_t)j * 4 + 1];
        out[p * 4 + 2] = (float)boxesD[(size_t)j * 4 + 2];
        out[p * 4 + 3] = (float)boxesD[(size_t)j * 4 + 3];
      }
      ++p;
    }
  }
}

extern "C" void kernel_launch(void* const* d_in, const int* in_sizes, int n_in,
                              void* d_out, int out_size, void* d_ws, size_t ws_size,
                              hipStream_t stream) {
  const float* f0   = (const float*)d_in[1];
  const float* f1   = (const float*)d_in[2];
  const float* f2   = (const float*)d_in[3];
  const float* f3   = (const float*)d_in[4];
  const float* f4   = (const float*)d_in[5];
  const float* w0   = (const float*)d_in[6];
  const float* b0   = (const float*)d_in[7];
  const float* wcls = (const float*)d_in[8];
  const float* bcls = (const float*)d_in[9];
  const float* wbox = (const float*)d_in[10];
  const float* bbox = (const float*)d_in[11];
  float* out = (float*)d_out;
  char* ws = (char*)d_ws;

  size_t off = 0;
  auto alloc = [&](size_t bytes) { size_t o = off; off += (bytes + 255) & ~(size_t)255; return o; };
  size_t off_scr  = alloc((size_t)A_TOTAL * 4);
  size_t off_wt   = alloc((size_t)256 * 2304 * 8);
  size_t off_wk   = alloc((size_t)256 * 2304 * 2);
  size_t off_hp   = alloc((size_t)4 * PIXMAX * 256 * 8);
  size_t off_ci   = alloc((size_t)CANDMAX * 4);
  size_t off_ck   = alloc((size_t)CANDMAX * 8);
  size_t off_cp   = alloc((size_t)CANDMAX * 4);
  size_t off_cd   = alloc((size_t)CANDMAX * 4 * 8);
  size_t off_pl   = alloc((size_t)PIXMAX * 4);
  size_t off_pm   = alloc((size_t)NPIX * 4);
  size_t off_box  = alloc((size_t)KTOP * 4 * 8);
  size_t off_keep = alloc((size_t)KTOP * 4);
  size_t off_mask = alloc((size_t)KTOP * NWORDS * 8);
  size_t off_bcnt = alloc((size_t)1024 * 4);
  size_t off_boff = alloc((size_t)1024 * 4);
  size_t off_bcp  = alloc((size_t)1024 * 4);
  size_t off_bop  = alloc((size_t)1024 * 4);
  size_t off_bins = alloc((size_t)NBINS * 4);
  size_t off_sub  = alloc((size_t)256 * 4);
  size_t off_meta = alloc((size_t)64 * 4);
  size_t off_end  = off;
  (void)in_sizes; (void)n_in; (void)out_size; (void)ws_size;

  float*  scr       = (float*)(ws + off_scr);
  double* wt64      = (double*)(ws + off_wt);
  ushort* wkf       = (ushort*)(ws + off_wk);
  double* hpart     = (double*)(ws + off_hp);
  u32*    candIdx   = (u32*)(ws + off_ci);
  u64*    candKey   = (u64*)(ws + off_ck);
  u32*    candPack  = (u32*)(ws + off_cp);
  double* candDelta = (double*)(ws + off_cd);
  u32*    pixList   = (u32*)(ws + off_pl);
  u32*    pixMap    = (u32*)(ws + off_pm);
  double* boxesD    = (double*)(ws + off_box);
  u32*    keep      = (u32*)(ws + off_keep);
  u64*    maskA     = (u64*)(ws + off_mask);
  u32*    blkCnt    = (u32*)(ws + off_bcnt);
  u32*    blkOff    = (u32*)(ws + off_boff);
  u32*    blkCntP   = (u32*)(ws + off_bcp);
  u32*    blkOffP   = (u32*)(ws + off_bop);
  u32*    bins      = (u32*)(ws + off_bins);
  u32*    sub       = (u32*)(ws + off_sub);
  u32*    meta      = (u32*)(ws + off_meta);

  hipMemsetAsync(ws + off_bins, 0, off_end - off_bins, stream);

  k_prep_w<<<2304, 256, 0, stream>>>(w0, wt64, wkf);
  k_conv_mfma<<<1364, 256, 0, stream>>>(f0, f1, f2, f3, f4, wkf, b0, wcls, bcls, scr);
  k_hist1<<<64, 256, 0, stream>>>(scr, bins);
  k_scan1<<<1, 256, 0, stream>>>(bins, meta);
  k_hist2<<<1023, 256, 0, stream>>>(scr, meta, sub);
  k_scan2<<<1, 64, 0, stream>>>(sub, meta);
  k_cnt2<<<1023, 256, 0, stream>>>(scr, meta, blkCnt, blkCntP);
  k_scanblk2<<<1, 1024, 0, stream>>>(blkCnt, blkOff, meta + 1, blkCntP, blkOffP, meta + 4);
  k_fill2<<<1023, 256, 0, stream>>>(scr, meta, blkOff, blkOffP, candIdx, pixList, pixMap);
  k_hidden<<<(PIXMAX / 32) * 4, 256, 0, stream>>>(f0, f1, f2, f3, f4, wt64, pixList, meta, hpart);
  k_heads<<<CANDMAX / 8, 256, 0, stream>>>(wcls, bcls, wbox, bbox, b0, candIdx, pixMap, meta,
                                           hpart, candKey, candPack, candDelta);
  k_rank<<<CANDMAX / 32, 256, 0, stream>>>(candKey, candPack, candDelta, boxesD);
  k_mask<<<dim3(NWORDS, NWORDS), 64, 0, stream>>>(boxesD, maskA);
  k_nms_reduce<<<1, 1024, 0, stream>>>(maskA, keep);
  k_emit<<<1, 1024, 0, stream>>>(keep, boxesD, out);
}